// Round 8
// baseline (256.072 us; speedup 1.0000x reference)
//
#include <hip/hip_runtime.h>
#include <hip/hip_bf16.h>
#include <math.h>

static constexpr int NN = 30000;   // nodes
static constexpr int NF = 512;     // in features
static constexpr int NH = 128;     // hidden
static constexpr int NC = 64;      // classes

typedef unsigned int uint32;
typedef __attribute__((ext_vector_type(8))) short bf16x8;
typedef __attribute__((ext_vector_type(4))) float f32x4;

__device__ __forceinline__ unsigned short bfbits(float f) {
  __hip_bfloat16 h = __float2bfloat16(f);   // RNE
  return *reinterpret_cast<unsigned short*>(&h);
}

// monotone key for one bf16 (u16 in low bits): order(key) == order(float)
__device__ __forceinline__ uint32 tokey1(uint32 b) {
  return b ^ (0x8000u | ((b >> 15) * 0x7FFFu));
}
// inverse: key (u16, <0x10000) -> fp32 value of the bf16
__device__ __forceinline__ float keytof(uint32 k) {
  const uint32 b = k ^ (0xFFFFu - ((k >> 15) & 1u) * 0x7FFFu);
  return __uint_as_float(b << 16);
}

// packed u16 min/max (VOP3P); each u32 holds two independent keys
__device__ __forceinline__ uint32 pkmin(uint32 a, uint32 b) {
  uint32 r; asm("v_pk_min_u16 %0, %1, %2" : "=v"(r) : "v"(a), "v"(b)); return r;
}
__device__ __forceinline__ uint32 pkmax(uint32 a, uint32 b) {
  uint32 r; asm("v_pk_max_u16 %0, %1, %2" : "=v"(r) : "v"(a), "v"(b)); return r;
}
__device__ __forceinline__ void cswapk(uint32& a, uint32& b) {
  const uint32 mn = pkmin(a, b), mx = pkmax(a, b);
  a = mn; b = mx;
}

// rank-15/16 of 32 packed key-pairs: bitonic-sort each 16-half, merge identity.
__device__ __forceinline__ void medselk(uint32 v[32], uint32& m15, uint32& m16) {
  #pragma unroll
  for (int k = 2; k <= 16; k <<= 1) {
    #pragma unroll
    for (int j = k >> 1; j > 0; j >>= 1) {
      #pragma unroll
      for (int h = 0; h < 2; ++h) {
        #pragma unroll
        for (int i = 0; i < 16; ++i) {
          const int l = i ^ j;
          if (l > i) {
            const int a = h * 16 + i, b = h * 16 + l;
            if ((i & k) == 0) cswapk(v[a], v[b]);
            else              cswapk(v[b], v[a]);
          }
        }
      }
    }
  }
  m15 = pkmin(v[0], v[31]);
  m16 = pkmax(v[0], v[31]);
  #pragma unroll
  for (int i = 1; i < 16; ++i) {
    m15 = pkmax(m15, pkmin(v[i], v[31 - i]));
    m16 = pkmin(m16, pkmax(v[i], v[31 - i]));
  }
}

// ---------------- k0: prep W1 (bf16 MFMA-fragment order) + W2 transpose ----------------
// Bp element index = ((kt*8 + nt)*64 + lane)*8 + j, lane = ks*16 + ct,
// maps W1[k = kt*32 + ks*8 + j][col = nt*16 + ct].  W2T[c][kk] = W2[kk][c].
__global__ __launch_bounds__(256) void k0_prep(const float* __restrict__ W1,
                                               const float* __restrict__ W2,
                                               unsigned short* __restrict__ Bp,
                                               float* __restrict__ W2T) {
  const int g = blockIdx.x * 256 + threadIdx.x;
  if (g < 8192) {
    const int kt = g >> 9;
    const int r  = g & 511;
    const int nt = r >> 6;
    const int l  = r & 63;
    const int ks = l >> 4;
    const int ct = l & 15;
    alignas(16) unsigned short t[8];
    #pragma unroll
    for (int j = 0; j < 8; ++j)
      t[j] = bfbits(W1[(kt * 32 + ks * 8 + j) * NH + nt * 16 + ct]);
    *reinterpret_cast<uint4*>(&Bp[(size_t)g * 8]) = *reinterpret_cast<const uint4*>(t);
  } else {
    const int t  = g - 8192;       // 0..8191
    const int c  = t >> 7;
    const int kk = t & 127;
    W2T[c * NH + kk] = W2[kk * NC + c];
  }
}

// ---------------- k1: h0k = key(bf16(x @ W1)) via MFMA, no LDS ----------------
// 469 blocks x 4 waves; wave = 16 rows x 128 cols; full A-row prefetch.
__global__ __launch_bounds__(256) void k1_gemm1(const float* __restrict__ x,
                                                const unsigned short* __restrict__ Bp,
                                                unsigned short* __restrict__ h0k) {
  const int tid = threadIdx.x;
  const int w   = tid >> 6;
  const int l   = tid & 63;
  const int m0  = blockIdx.x * 64 + w * 16;

  int arow = m0 + (l & 15);
  if (arow >= NN) arow = NN - 1;          // tail clamp; stores guarded
  const float* xrow = x + (size_t)arow * NF + (l >> 4) * 8;

  f32x4 acc[8];
  #pragma unroll
  for (int nt = 0; nt < 8; ++nt) acc[nt] = (f32x4){0.f, 0.f, 0.f, 0.f};

  // issue ALL A loads up front: one HBM latency exposure per wave
  float4 abuf[16][2];
  #pragma unroll
  for (int kt = 0; kt < 16; ++kt) {
    abuf[kt][0] = *reinterpret_cast<const float4*>(xrow + kt * 32);
    abuf[kt][1] = *reinterpret_cast<const float4*>(xrow + kt * 32 + 4);
  }

  #pragma unroll
  for (int kt = 0; kt < 16; ++kt) {
    union { bf16x8 v; unsigned short u[8]; } A;
    const float av[8] = {abuf[kt][0].x, abuf[kt][0].y, abuf[kt][0].z, abuf[kt][0].w,
                         abuf[kt][1].x, abuf[kt][1].y, abuf[kt][1].z, abuf[kt][1].w};
    #pragma unroll
    for (int j = 0; j < 8; ++j) A.u[j] = bfbits(av[j]);

    const unsigned short* bbase = Bp + (size_t)kt * 4096 + l * 8;
    #pragma unroll
    for (int nt = 0; nt < 8; ++nt) {
      const bf16x8 B = *reinterpret_cast<const bf16x8*>(bbase + nt * 512);
      acc[nt] = __builtin_amdgcn_mfma_f32_16x16x32_bf16(A.v, B, acc[nt], 0, 0, 0);
    }
  }

  // C/D layout: col = l&15, row = (l>>4)*4 + q  [measured m89/m91]
  const int rbase = m0 + (l >> 4) * 4;
  const int cbase = l & 15;
  #pragma unroll
  for (int q = 0; q < 4; ++q) {
    const int rr = rbase + q;
    if (rr < NN) {
      #pragma unroll
      for (int nt = 0; nt < 8; ++nt) {
        const uint32 b = bfbits(acc[nt][q]);
        h0k[(size_t)rr * NH + nt * 16 + cbase] = (unsigned short)tokey1(b);
      }
    }
  }
}

// ---------------- k2: h = relu(median33+b1); zk = key(bf16(h @ W2T)) ----------------
// 4 nodes/block, 64 lanes/node, 2 features/lane; packed-key median.
__global__ __launch_bounds__(256) void k2_median1_gemm2(const unsigned short* __restrict__ h0k,
                                                        const int* __restrict__ nbr,
                                                        const float* __restrict__ b1,
                                                        const float* __restrict__ W2T,
                                                        unsigned short* __restrict__ zk) {
  __shared__ int   nb[4][32];
  __shared__ float hs[4][NH];
  const int tid  = threadIdx.x;
  const int g    = tid >> 6;
  const int lane = tid & 63;
  const int i    = blockIdx.x * 4 + g;

  if (lane < 32) nb[g][lane] = nbr[i * 32 + lane];
  __syncthreads();

  const uint32* hk = reinterpret_cast<const uint32*>(h0k);  // 64 u32 per row
  uint32 pr[32];
  #pragma unroll
  for (int k = 0; k < 32; ++k) {
    const int nbk = __builtin_amdgcn_readfirstlane(nb[g][k]);  // wave-uniform -> SALU path
    int idx = i + nbk + 1;
    if (idx >= NN) idx -= NN;
    pr[k] = hk[idx * 64 + lane];
  }
  const uint32 ps = hk[i * 64 + lane];

  uint32 m15, m16;
  medselk(pr, m15, m16);
  const uint32 medk = pkmin(pkmax(ps, m15), m16);   // clamp self into [m15,m16]

  const float hA = fmaxf(keytof(medk & 0xFFFFu) + b1[lane * 2 + 0], 0.f);
  const float hB = fmaxf(keytof(medk >> 16)     + b1[lane * 2 + 1], 0.f);
  hs[g][lane * 2 + 0] = hA;
  hs[g][lane * 2 + 1] = hB;
  __syncthreads();

  // GEMM2: one output column per lane; W2T row contiguous -> float4 loads
  const float4* w4 = reinterpret_cast<const float4*>(W2T + lane * NH);
  const float4* h4 = reinterpret_cast<const float4*>(&hs[g][0]);
  float acc = 0.f;
  #pragma unroll
  for (int t = 0; t < 32; ++t) {
    const float4 wv = w4[t];
    const float4 hv = h4[t];
    acc = fmaf(wv.x, hv.x, acc);
    acc = fmaf(wv.y, hv.y, acc);
    acc = fmaf(wv.z, hv.z, acc);
    acc = fmaf(wv.w, hv.w, acc);
  }
  zk[i * NC + lane] = (unsigned short)tokey1(bfbits(acc));
}

// ---------------- k3: out = log_softmax(median33(zk)+b2) ----------------
// 8 nodes/block, 32 lanes/node, 2 classes/lane; packed-key median.
__global__ __launch_bounds__(256) void k3_median2_lsm(const unsigned short* __restrict__ zk,
                                                      const int* __restrict__ nbr,
                                                      const float* __restrict__ b2,
                                                      float* __restrict__ out) {
  __shared__ int nb[8][32];
  const int tid  = threadIdx.x;
  const int g    = tid >> 5;
  const int lane = tid & 31;
  const int i    = blockIdx.x * 8 + g;

  nb[g][lane] = nbr[i * 32 + lane];
  __syncthreads();

  const uint32* zz = reinterpret_cast<const uint32*>(zk);   // 32 u32 per row
  uint32 pr[32];
  #pragma unroll
  for (int k = 0; k < 32; ++k) {
    int idx = i + nb[g][k] + 1;       // g differs across wave halves: keep per-lane math
    if (idx >= NN) idx -= NN;
    pr[k] = zz[idx * 32 + lane];
  }
  const uint32 ps = zz[i * 32 + lane];

  uint32 m15, m16;
  medselk(pr, m15, m16);
  const uint32 medk = pkmin(pkmax(ps, m15), m16);

  const float oA = keytof(medk & 0xFFFFu) + b2[lane * 2 + 0];
  const float oB = keytof(medk >> 16)     + b2[lane * 2 + 1];

  // log-softmax over 64 classes = 2/lane x 32 lanes
  float m = fmaxf(oA, oB);
  #pragma unroll
  for (int d = 1; d < 32; d <<= 1) m = fmaxf(m, __shfl_xor(m, d, 32));
  float s = __expf(oA - m) + __expf(oB - m);
  #pragma unroll
  for (int d = 1; d < 32; d <<= 1) s += __shfl_xor(s, d, 32);
  const float ls = __logf(s);

  *reinterpret_cast<float2*>(&out[i * NC + lane * 2]) =
      make_float2(oA - m - ls, oB - m - ls);
}

// ---------------- launch ----------------
extern "C" void kernel_launch(void* const* d_in, const int* in_sizes, int n_in,
                              void* d_out, int out_size, void* d_ws, size_t ws_size,
                              hipStream_t stream) {
  const float* x   = (const float*)d_in[0];
  const int*   nbr = (const int*)d_in[1];
  const float* W1  = (const float*)d_in[2];
  const float* b1  = (const float*)d_in[3];
  const float* W2  = (const float*)d_in[4];
  const float* b2  = (const float*)d_in[5];
  float* outp = (float*)d_out;

  unsigned short* h0k = (unsigned short*)d_ws;                                  // 7.68 MB
  unsigned short* zk  = (unsigned short*)((char*)d_ws + (size_t)NN * NH * 2);   // 3.84 MB
  unsigned short* Bp  = (unsigned short*)((char*)d_ws + (size_t)NN * (NH + NC) * 2); // 128 KB
  float*          W2T = (float*)((char*)d_ws + (size_t)NN * (NH + NC) * 2 + 131072); // 32 KB

  k0_prep<<<64, 256, 0, stream>>>(W1, W2, Bp, W2T);
  k1_gemm1<<<(NN + 63) / 64, 256, 0, stream>>>(x, Bp, h0k);
  k2_median1_gemm2<<<NN / 4, 256, 0, stream>>>(h0k, nbr, b1, W2T, zk);
  k3_median2_lsm<<<NN / 8, 256, 0, stream>>>(zk, nbr, b2, outp);
}

// Round 11
// 254.188 us; speedup vs baseline: 1.0074x; 1.0074x over previous
//
#include <hip/hip_runtime.h>
#include <hip/hip_bf16.h>
#include <math.h>

static constexpr int NN = 30000;   // nodes
static constexpr int NF = 512;     // in features
static constexpr int NH = 128;     // hidden
static constexpr int NC = 64;      // classes

typedef unsigned int uint32;
typedef __attribute__((ext_vector_type(8))) short bf16x8;
typedef __attribute__((ext_vector_type(4))) float f32x4;
typedef __attribute__((ext_vector_type(2))) unsigned short u16x2;

__device__ __forceinline__ unsigned short bfbits(float f) {
  __hip_bfloat16 h = __float2bfloat16(f);   // RNE
  return *reinterpret_cast<unsigned short*>(&h);
}

// monotone key for one bf16 (u16): order(key) == order(float)
__device__ __forceinline__ uint32 tokey1(uint32 b) {
  return b ^ (0x8000u | ((b >> 15) * 0x7FFFu));
}
// inverse: key (u16) -> fp32 value of the bf16
__device__ __forceinline__ float keytof(uint32 k) {
  const uint32 b = k ^ (0xFFFFu - ((k >> 15) & 1u) * 0x7FFFu);
  return __uint_as_float(b << 16);
}

__device__ __forceinline__ u16x2 as_u16x2(uint32 v) {
  union { uint32 u; u16x2 p; } c; c.u = v; return c.p;
}

// packed u16 min/max -> v_pk_min_u16 / v_pk_max_u16 via LLVM umin/umax <2 x i16>
__device__ __forceinline__ u16x2 pkmin(u16x2 a, u16x2 b) {
  return __builtin_elementwise_min(a, b);
}
__device__ __forceinline__ u16x2 pkmax(u16x2 a, u16x2 b) {
  return __builtin_elementwise_max(a, b);
}
__device__ __forceinline__ void cswapk(u16x2& a, u16x2& b) {
  const u16x2 mn = pkmin(a, b), mx = pkmax(a, b);
  a = mn; b = mx;
}

// rank-15/16 of 32 packed key-pairs: bitonic-sort each 16-half, merge identity.
__device__ __forceinline__ void medselk(u16x2 v[32], u16x2& m15, u16x2& m16) {
  #pragma unroll
  for (int k = 2; k <= 16; k <<= 1) {
    #pragma unroll
    for (int j = k >> 1; j > 0; j >>= 1) {
      #pragma unroll
      for (int h = 0; h < 2; ++h) {
        #pragma unroll
        for (int i = 0; i < 16; ++i) {
          const int l = i ^ j;
          if (l > i) {
            const int a = h * 16 + i, b = h * 16 + l;
            if ((i & k) == 0) cswapk(v[a], v[b]);
            else              cswapk(v[b], v[a]);
          }
        }
      }
    }
  }
  m15 = pkmin(v[0], v[31]);
  m16 = pkmax(v[0], v[31]);
  #pragma unroll
  for (int i = 1; i < 16; ++i) {
    m15 = pkmax(m15, pkmin(v[i], v[31 - i]));
    m16 = pkmin(m16, pkmax(v[i], v[31 - i]));
  }
}

// ---------------- k0: prep W1 (bf16 MFMA-fragment order) + W2 transpose ----------------
// Bp element index = ((kt*8 + nt)*64 + lane)*8 + j, lane = ks*16 + ct,
// maps W1[k = kt*32 + ks*8 + j][col = nt*16 + ct].  W2T[c][kk] = W2[kk][c].
__global__ __launch_bounds__(256) void k0_prep(const float* __restrict__ W1,
                                               const float* __restrict__ W2,
                                               unsigned short* __restrict__ Bp,
                                               float* __restrict__ W2T) {
  const int g = blockIdx.x * 256 + threadIdx.x;
  if (g < 8192) {
    const int kt = g >> 9;
    const int r  = g & 511;
    const int nt = r >> 6;
    const int l  = r & 63;
    const int ks = l >> 4;
    const int ct = l & 15;
    alignas(16) unsigned short t[8];
    #pragma unroll
    for (int j = 0; j < 8; ++j)
      t[j] = bfbits(W1[(kt * 32 + ks * 8 + j) * NH + nt * 16 + ct]);
    *reinterpret_cast<uint4*>(&Bp[(size_t)g * 8]) = *reinterpret_cast<const uint4*>(t);
  } else {
    const int t  = g - 8192;       // 0..8191
    const int c  = t >> 7;
    const int kk = t & 127;
    W2T[c * NH + kk] = W2[kk * NC + c];
  }
}

// ---------------- k1: h0k = key(bf16(x @ W1)) via MFMA, no LDS ----------------
// 469 blocks x 4 waves; wave = 16 rows x 128 cols; full A-row prefetch.
__global__ __launch_bounds__(256) void k1_gemm1(const float* __restrict__ x,
                                                const unsigned short* __restrict__ Bp,
                                                unsigned short* __restrict__ h0k) {
  const int tid = threadIdx.x;
  const int w   = tid >> 6;
  const int l   = tid & 63;
  const int m0  = blockIdx.x * 64 + w * 16;

  int arow = m0 + (l & 15);
  if (arow >= NN) arow = NN - 1;          // tail clamp; stores guarded
  const float* xrow = x + (size_t)arow * NF + (l >> 4) * 8;

  f32x4 acc[8];
  #pragma unroll
  for (int nt = 0; nt < 8; ++nt) acc[nt] = (f32x4){0.f, 0.f, 0.f, 0.f};

  // issue ALL A loads up front: one HBM latency exposure per wave
  float4 abuf[16][2];
  #pragma unroll
  for (int kt = 0; kt < 16; ++kt) {
    abuf[kt][0] = *reinterpret_cast<const float4*>(xrow + kt * 32);
    abuf[kt][1] = *reinterpret_cast<const float4*>(xrow + kt * 32 + 4);
  }

  #pragma unroll
  for (int kt = 0; kt < 16; ++kt) {
    union { bf16x8 v; unsigned short u[8]; } A;
    const float av[8] = {abuf[kt][0].x, abuf[kt][0].y, abuf[kt][0].z, abuf[kt][0].w,
                         abuf[kt][1].x, abuf[kt][1].y, abuf[kt][1].z, abuf[kt][1].w};
    #pragma unroll
    for (int j = 0; j < 8; ++j) A.u[j] = bfbits(av[j]);

    const unsigned short* bbase = Bp + (size_t)kt * 4096 + l * 8;
    #pragma unroll
    for (int nt = 0; nt < 8; ++nt) {
      const bf16x8 B = *reinterpret_cast<const bf16x8*>(bbase + nt * 512);
      acc[nt] = __builtin_amdgcn_mfma_f32_16x16x32_bf16(A.v, B, acc[nt], 0, 0, 0);
    }
  }

  // C/D layout: col = l&15, row = (l>>4)*4 + q  [measured m89/m91]
  const int rbase = m0 + (l >> 4) * 4;
  const int cbase = l & 15;
  #pragma unroll
  for (int q = 0; q < 4; ++q) {
    const int rr = rbase + q;
    if (rr < NN) {
      #pragma unroll
      for (int nt = 0; nt < 8; ++nt) {
        const uint32 b = bfbits(acc[nt][q]);
        h0k[(size_t)rr * NH + nt * 16 + cbase] = (unsigned short)tokey1(b);
      }
    }
  }
}

// ---------------- k2: h = relu(median33+b1); zk = key(bf16(h @ W2T)) ----------------
// 4 nodes/block, 64 lanes/node, 2 features/lane; packed-key median.
__global__ __launch_bounds__(256) void k2_median1_gemm2(const unsigned short* __restrict__ h0k,
                                                        const int* __restrict__ nbr,
                                                        const float* __restrict__ b1,
                                                        const float* __restrict__ W2T,
                                                        unsigned short* __restrict__ zk) {
  __shared__ int   nb[4][32];
  __shared__ float hs[4][NH];
  const int tid  = threadIdx.x;
  const int g    = tid >> 6;
  const int lane = tid & 63;
  const int i    = blockIdx.x * 4 + g;

  if (lane < 32) nb[g][lane] = nbr[i * 32 + lane];
  __syncthreads();

  const uint32* hk = reinterpret_cast<const uint32*>(h0k);  // 64 u32 per row
  u16x2 pr[32];
  #pragma unroll
  for (int k = 0; k < 32; ++k) {
    int idx = i + nb[g][k] + 1;
    if (idx >= NN) idx -= NN;
    pr[k] = as_u16x2(hk[idx * 64 + lane]);
  }
  const u16x2 ps = as_u16x2(hk[i * 64 + lane]);

  u16x2 m15, m16;
  medselk(pr, m15, m16);
  const u16x2 medk = pkmin(pkmax(ps, m15), m16);   // clamp self into [m15,m16]

  const float hA = fmaxf(keytof(medk.x) + b1[lane * 2 + 0], 0.f);
  const float hB = fmaxf(keytof(medk.y) + b1[lane * 2 + 1], 0.f);
  hs[g][lane * 2 + 0] = hA;
  hs[g][lane * 2 + 1] = hB;
  __syncthreads();

  // GEMM2: one output column per lane; W2T row contiguous -> float4 loads
  const float4* w4 = reinterpret_cast<const float4*>(W2T + lane * NH);
  const float4* h4 = reinterpret_cast<const float4*>(&hs[g][0]);
  float acc = 0.f;
  #pragma unroll
  for (int t = 0; t < 32; ++t) {
    const float4 wv = w4[t];
    const float4 hv = h4[t];
    acc = fmaf(wv.x, hv.x, acc);
    acc = fmaf(wv.y, hv.y, acc);
    acc = fmaf(wv.z, hv.z, acc);
    acc = fmaf(wv.w, hv.w, acc);
  }
  zk[i * NC + lane] = (unsigned short)tokey1(bfbits(acc));
}

// ---------------- k3: out = log_softmax(median33(zk)+b2) ----------------
// 8 nodes/block, 32 lanes/node, 2 classes/lane; packed-key median.
__global__ __launch_bounds__(256) void k3_median2_lsm(const unsigned short* __restrict__ zk,
                                                      const int* __restrict__ nbr,
                                                      const float* __restrict__ b2,
                                                      float* __restrict__ out) {
  __shared__ int nb[8][32];
  const int tid  = threadIdx.x;
  const int g    = tid >> 5;
  const int lane = tid & 31;
  const int i    = blockIdx.x * 8 + g;

  nb[g][lane] = nbr[i * 32 + lane];
  __syncthreads();

  const uint32* zz = reinterpret_cast<const uint32*>(zk);   // 32 u32 per row
  u16x2 pr[32];
  #pragma unroll
  for (int k = 0; k < 32; ++k) {
    int idx = i + nb[g][k] + 1;
    if (idx >= NN) idx -= NN;
    pr[k] = as_u16x2(zz[idx * 32 + lane]);
  }
  const u16x2 ps = as_u16x2(zz[i * 32 + lane]);

  u16x2 m15, m16;
  medselk(pr, m15, m16);
  const u16x2 medk = pkmin(pkmax(ps, m15), m16);

  const float oA = keytof(medk.x) + b2[lane * 2 + 0];
  const float oB = keytof(medk.y) + b2[lane * 2 + 1];

  // log-softmax over 64 classes = 2/lane x 32 lanes
  float m = fmaxf(oA, oB);
  #pragma unroll
  for (int d = 1; d < 32; d <<= 1) m = fmaxf(m, __shfl_xor(m, d, 32));
  float s = __expf(oA - m) + __expf(oB - m);
  #pragma unroll
  for (int d = 1; d < 32; d <<= 1) s += __shfl_xor(s, d, 32);
  const float ls = __logf(s);

  *reinterpret_cast<float2*>(&out[i * NC + lane * 2]) =
      make_float2(oA - m - ls, oB - m - ls);
}

// ---------------- launch ----------------
extern "C" void kernel_launch(void* const* d_in, const int* in_sizes, int n_in,
                              void* d_out, int out_size, void* d_ws, size_t ws_size,
                              hipStream_t stream) {
  const float* x   = (const float*)d_in[0];
  const int*   nbr = (const int*)d_in[1];
  const float* W1  = (const float*)d_in[2];
  const float* b1  = (const float*)d_in[3];
  const float* W2  = (const float*)d_in[4];
  const float* b2  = (const float*)d_in[5];
  float* outp = (float*)d_out;

  unsigned short* h0k = (unsigned short*)d_ws;                                  // 7.68 MB
  unsigned short* zk  = (unsigned short*)((char*)d_ws + (size_t)NN * NH * 2);   // 3.84 MB
  unsigned short* Bp  = (unsigned short*)((char*)d_ws + (size_t)NN * (NH + NC) * 2); // 128 KB
  float*          W2T = (float*)((char*)d_ws + (size_t)NN * (NH + NC) * 2 + 131072); // 32 KB

  k0_prep<<<64, 256, 0, stream>>>(W1, W2, Bp, W2T);
  k1_gemm1<<<(NN + 63) / 64, 256, 0, stream>>>(x, Bp, h0k);
  k2_median1_gemm2<<<NN / 4, 256, 0, stream>>>(h0k, nbr, b1, W2T, zk);
  k3_median2_lsm<<<NN / 8, 256, 0, stream>>>(zk, nbr, b2, outp);
}